// Round 1
// baseline (943.379 us; speedup 1.0000x reference)
//
#include <hip/hip_runtime.h>
#include <math.h>

#define NN 10000
#define NE 160000
#define NB 4
#define NH 4
#define NDH 64
#define ND 256
#define NT (NN * NB * NH)   // 160000 (n,b,h) triples
#define NM (NB * NN)        // 40000 GEMM rows

// ---------------- CSR build ----------------
__global__ __launch_bounds__(256) void k_deg(const int* __restrict__ dst, int* __restrict__ deg) {
  int e = blockIdx.x * 256 + threadIdx.x;
  if (e < NE) atomicAdd(&deg[dst[e]], 1);
}

__global__ __launch_bounds__(1024) void k_scan(const int* __restrict__ deg, int* __restrict__ offs) {
  __shared__ int tmp[1024];
  __shared__ int carry_s;
  if (threadIdx.x == 0) carry_s = 0;
  __syncthreads();
  for (int base = 0; base < NN; base += 1024) {
    int i = base + (int)threadIdx.x;
    int v = (i < NN) ? deg[i] : 0;
    int c0 = carry_s;
    tmp[threadIdx.x] = v;
    __syncthreads();
    for (int s = 1; s < 1024; s <<= 1) {
      int add = (threadIdx.x >= (unsigned)s) ? tmp[threadIdx.x - s] : 0;
      __syncthreads();
      tmp[threadIdx.x] += add;
      __syncthreads();
    }
    if (i < NN) offs[i] = c0 + tmp[threadIdx.x] - v;   // exclusive
    int tot = tmp[1023];
    __syncthreads();
    if (threadIdx.x == 0) carry_s = c0 + tot;
    __syncthreads();
  }
  if (threadIdx.x == 0) offs[NN] = carry_s;
}

__global__ __launch_bounds__(256) void k_scatter(const int* __restrict__ src, const int* __restrict__ dst,
                                                 const float* __restrict__ w, const int* __restrict__ offs,
                                                 int* __restrict__ cursor, int* __restrict__ csr_src,
                                                 float* __restrict__ csr_w) {
  int e = blockIdx.x * 256 + threadIdx.x;
  if (e < NE) {
    int d = dst[e];
    int slot = offs[d] + atomicAdd(&cursor[d], 1);
    csr_src[slot] = src[e];
    csr_w[slot] = w[e];
  }
}

// ---------------- weight fusion ----------------
// fw[h*64+o, d] = sum_f ofc_w[o,f] * fc_w[h*64+f, d]
__global__ __launch_bounds__(256) void k_fuse_w(const float* __restrict__ fc_w, const float* __restrict__ ofc_w,
                                                float* __restrict__ fw) {
  int r = blockIdx.x;        // 0..255 = h*64+o
  int d = threadIdx.x;       // 0..255
  int h = r >> 6, o = r & 63;
  float acc = 0.f;
  for (int f = 0; f < 64; ++f)
    acc = fmaf(ofc_w[(o << 6) + f], fc_w[(((h << 6) + f) << 8) + d], acc);
  fw[(r << 8) + d] = acc;
}

// alf rows 0..3 = al_fused[h, d], rows 4..7 = ar_fused[h, d]
__global__ __launch_bounds__(256) void k_fuse_attn(const float* __restrict__ fc_w,
                                                   const float* __restrict__ al, const float* __restrict__ ar,
                                                   float* __restrict__ alf) {
  int r = blockIdx.x;        // 0..7
  int d = threadIdx.x;
  int h = r & 3;
  const float* a = (r < 4) ? al : ar;
  float acc = 0.f;
  for (int f = 0; f < 64; ++f)
    acc = fmaf(a[(h << 6) + f], fc_w[(((h << 6) + f) << 8) + d], acc);
  alf[(r << 8) + d] = acc;
}

// ---------------- GEMM: out[orow, c] = sum_k A[ra, k] * W[c, k] (+bias) ----------------
// A[ra,k] = (k<half ? pA0[ra*lda+k] : pA1[ra*lda+k-half]); orow = permute ? (ra%NN)*4+ra/NN : ra
__global__ __launch_bounds__(256) void k_gemm(
    const float* __restrict__ pA0, const float* __restrict__ pA1,
    int lda, int half, int K,
    const float* __restrict__ W, int ldw,
    const float* __restrict__ bias,
    float* __restrict__ outp, int ldo, int permute)
{
  __shared__ float As[16][68];
  __shared__ float Bs[16][136];
  const int tid = threadIdx.x;
  const int lk = tid & 15;
  const int lm = tid >> 4;
  const int ra0 = blockIdx.x * 64;
  const int c0 = blockIdx.y * 128;
  float acc[4][8];
#pragma unroll
  for (int i = 0; i < 4; ++i)
#pragma unroll
    for (int j = 0; j < 8; ++j) acc[i][j] = 0.f;

  const int ty4 = (tid >> 4) & 0xFC;  // placeholder, recomputed below
  (void)ty4;

  for (int k0 = 0; k0 < K; k0 += 16) {
    int k = k0 + lk;
    const float* pa = (k < half) ? (pA0 + (size_t)lda * (ra0 + lm) + k)
                                 : (pA1 + (size_t)lda * (ra0 + lm) + (k - half));
#pragma unroll
    for (int j = 0; j < 4; ++j)
      As[lk][lm + 16 * j] = pa[(size_t)lda * 16 * j];
    const float* pb = W + (size_t)ldw * (c0 + lm) + k;
#pragma unroll
    for (int j = 0; j < 8; ++j)
      Bs[lk][lm + 16 * j] = pb[(size_t)ldw * 16 * j];
    __syncthreads();
    const int tm = (tid >> 4) << 2;   // 0..60
    const int tn = (tid & 15) << 3;   // 0..120
#pragma unroll
    for (int kk = 0; kk < 16; ++kk) {
      float4 av  = *(const float4*)&As[kk][tm];
      float4 bv0 = *(const float4*)&Bs[kk][tn];
      float4 bv1 = *(const float4*)&Bs[kk][tn + 4];
      float a_[4] = {av.x, av.y, av.z, av.w};
      float b_[8] = {bv0.x, bv0.y, bv0.z, bv0.w, bv1.x, bv1.y, bv1.z, bv1.w};
#pragma unroll
      for (int i = 0; i < 4; ++i)
#pragma unroll
        for (int j = 0; j < 8; ++j)
          acc[i][j] = fmaf(a_[i], b_[j], acc[i][j]);
    }
    __syncthreads();
  }
  const int tm = (tid >> 4) << 2;
  const int tn = (tid & 15) << 3;
#pragma unroll
  for (int i = 0; i < 4; ++i) {
    int ra = ra0 + tm + i;
    int orow = permute ? ((ra % NN) * NB + ra / NN) : ra;
    float* po = outp + (size_t)orow * ldo + c0 + tn;
#pragma unroll
    for (int j = 0; j < 8; ++j) {
      float v = acc[i][j];
      if (bias) v += bias[c0 + tn + j];
      po[j] = v;
    }
  }
}

// ---------------- el/er: el[n*16+b*4+h] = sum_d x[ra,d]*alf[h,d] ----------------
__global__ __launch_bounds__(256) void k_eler2(
    const float* __restrict__ pA0, const float* __restrict__ pA1, int lda, int half,
    const float* __restrict__ alf, float* __restrict__ el, float* __restrict__ er)
{
  int wid = threadIdx.x >> 6, lane = threadIdx.x & 63;
  int ra = blockIdx.x * 4 + wid;        // 0..39999 = b*NN+n
  int k0 = lane << 2;
  const float* p = (k0 < half) ? (pA0 + (size_t)ra * lda + k0)
                               : (pA1 + (size_t)ra * lda + (k0 - half));
  float4 xv = *(const float4*)p;
  int n = ra % NN, b = ra / NN;
  int tb = (n << 4) + (b << 2);
#pragma unroll
  for (int oi = 0; oi < 8; ++oi) {
    float4 av = *(const float4*)(alf + (oi << 8) + k0);
    float s = xv.x * av.x + xv.y * av.y + xv.z * av.z + xv.w * av.w;
#pragma unroll
    for (int k = 32; k; k >>= 1) s += __shfl_xor(s, k);
    if (lane == 0) {
      if (oi < 4) el[tb + oi] = s;
      else        er[tb + (oi - 4)] = s;
    }
  }
}

// ---------------- edge softmax + aggregate (+relu/bias epilogue) ----------------
// one wave per (n,b,h); lane = output channel o
__global__ __launch_bounds__(256) void k_edge(
    const float* __restrict__ featW, const float* __restrict__ el, const float* __restrict__ er,
    const int* __restrict__ csr_src, const float* __restrict__ csr_w, const int* __restrict__ offs,
    const float* __restrict__ b2, float* __restrict__ outl)
{
  int wid = threadIdx.x >> 6, lane = threadIdx.x & 63;
  int t = blockIdx.x * 4 + wid;          // n*16 + b*4 + h
  int n = t >> 4, b = (t >> 2) & 3, h = t & 3;
  int s0 = offs[n], s1 = offs[n + 1];
  float erv = er[t];
  // pass 1: max
  float m = -INFINITY;
  for (int e = s0 + lane; e < s1; e += 64) {
    float x = el[(csr_src[e] << 4) + (b << 2) + h] + erv;
    x = (x > 0.f) ? x : 0.1f * x;
    m = fmaxf(m, x * csr_w[e]);
  }
#pragma unroll
  for (int k = 32; k; k >>= 1) m = fmaxf(m, __shfl_xor(m, k));
  // pass 2: sum of exp
  float ssum = 0.f;
  for (int e = s0 + lane; e < s1; e += 64) {
    float x = el[(csr_src[e] << 4) + (b << 2) + h] + erv;
    x = (x > 0.f) ? x : 0.1f * x;
    ssum += __expf(x * csr_w[e] - m);
  }
#pragma unroll
  for (int k = 32; k; k >>= 1) ssum += __shfl_xor(ssum, k);
  float inv = (s1 > s0) ? 1.f / ssum : 0.f;
  // pass 3: weighted aggregate of featW (out_fc already folded in)
  float acc = 0.f;
  for (int e = s0; e < s1; ++e) {
    int sn = csr_src[e];
    float x = el[(sn << 4) + (b << 2) + h] + erv;
    x = (x > 0.f) ? x : 0.1f * x;
    float a = __expf(x * csr_w[e] - m) * inv;
    acc = fmaf(a, featW[((size_t)((sn << 4) + (b << 2) + h) << 6) + lane], acc);
  }
  float r2 = fmaxf(acc + b2[lane], 0.f);
  outl[((size_t)(b * NN + n) << 8) + (h << 6) + lane] = r2;
}

// ---------------- launch ----------------
extern "C" void kernel_launch(void* const* d_in, const int* in_sizes, int n_in,
                              void* d_out, int out_size, void* d_ws, size_t ws_size,
                              hipStream_t stream) {
  const float* sol    = (const float*)d_in[0];   // [2,4,10000,128]
  const float* w      = (const float*)d_in[1];   // [E]
  const float* fc_w   = (const float*)d_in[2];   // [2,256,256]
  const float* attn_l = (const float*)d_in[3];   // [2,4,64]
  const float* attn_r = (const float*)d_in[4];   // [2,4,64]
  const float* ofc_w  = (const float*)d_in[5];   // [2,64,64]
  const float* ofc_b  = (const float*)d_in[6];   // [2,64]
  const float* mlp_w  = (const float*)d_in[7];   // [256,512]
  const float* mlp_b  = (const float*)d_in[8];   // [256]
  const int*   d_src  = (const int*)d_in[9];     // [E]
  const int*   d_dst  = (const int*)d_in[10];    // [E]
  float* out = (float*)d_out;

  char* p = (char*)d_ws;
  auto alloc = [&](size_t bytes) { char* r = p; p += (bytes + 255) & ~(size_t)255; return r; };
  float* featW   = (float*)alloc((size_t)NT * NDH * 4);     // 40.96 MB
  float* out0    = (float*)alloc((size_t)NM * ND * 4);      // 40.96 MB
  float* out1    = (float*)alloc((size_t)NM * ND * 4);      // 40.96 MB
  float* el      = (float*)alloc((size_t)NT * 4);
  float* er      = (float*)alloc((size_t)NT * 4);
  int*   deg     = (int*)alloc((size_t)(NN + 1) * 4);
  int*   offs    = (int*)alloc((size_t)(NN + 1) * 4);
  int*   cursor  = (int*)alloc((size_t)NN * 4);
  int*   csr_src = (int*)alloc((size_t)NE * 4);
  float* csr_w   = (float*)alloc((size_t)NE * 4);
  float* fw      = (float*)alloc((size_t)ND * ND * 4);
  float* alf     = (float*)alloc((size_t)8 * ND * 4);
  if ((size_t)(p - (char*)d_ws) > ws_size) return;  // fail loudly (validation will catch)

  // CSR build (deterministic structure; intra-row order atomic-nondeterministic, fp-noise only)
  hipMemsetAsync(deg, 0, (size_t)NN * 4, stream);
  hipMemsetAsync(cursor, 0, (size_t)NN * 4, stream);
  k_deg<<<NE / 256, 256, 0, stream>>>(d_dst, deg);
  k_scan<<<1, 1024, 0, stream>>>(deg, offs);
  k_scatter<<<NE / 256, 256, 0, stream>>>(d_src, d_dst, w, offs, cursor, csr_src, csr_w);

  for (int l = 0; l < 2; ++l) {
    const float* fcl = fc_w + (size_t)l * ND * ND;
    k_fuse_w<<<256, 256, 0, stream>>>(fcl, ofc_w + (size_t)l * NDH * NDH, fw);
    k_fuse_attn<<<8, 256, 0, stream>>>(fcl, attn_l + (size_t)l * NH * NDH, attn_r + (size_t)l * NH * NDH, alf);
    const float* pA0; const float* pA1; int lda, half;
    if (l == 0) { pA0 = sol; pA1 = sol + (size_t)NB * NN * 128; lda = 128; half = 128; }
    else        { pA0 = out0; pA1 = out0; lda = 256; half = 256; }
    k_gemm<<<dim3(NM / 64, ND / 128), 256, 0, stream>>>(pA0, pA1, lda, half, ND,
                                                        fw, ND, nullptr, featW, ND, 1);
    k_eler2<<<NM / 4, 256, 0, stream>>>(pA0, pA1, lda, half, alf, el, er);
    k_edge<<<NT / 4, 256, 0, stream>>>(featW, el, er, csr_src, csr_w, offs,
                                       ofc_b + (size_t)l * NDH, (l == 0) ? out0 : out1);
  }

  // final MLP: out[b,n,o] = concat(out0,out1)[row,:512] . mlp_w[o,:] + mlp_b[o]
  k_gemm<<<dim3(NM / 64, ND / 128), 256, 0, stream>>>(out0, out1, 256, 256, 512,
                                                      mlp_w, 512, mlp_b, out, ND, 0);
}

// Round 2
// 634.018 us; speedup vs baseline: 1.4879x; 1.4879x over previous
//
#include <hip/hip_runtime.h>
#include <math.h>

#define NN 10000
#define NE 160000
#define NB 4
#define NH 4
#define NDH 64
#define ND 256
#define NT (NN * NB * NH)   // 160000 (n,b,h) triples
#define NM (NB * NN)        // 40000 GEMM rows
#define MAXC 64             // edge chunk per online-softmax step

// ---------------- CSR build ----------------
__global__ __launch_bounds__(256) void k_deg(const int* __restrict__ dst, int* __restrict__ deg) {
  int e = blockIdx.x * 256 + threadIdx.x;
  if (e < NE) atomicAdd(&deg[dst[e]], 1);
}

__global__ __launch_bounds__(1024) void k_scan(const int* __restrict__ deg, int* __restrict__ offs) {
  __shared__ int tmp[1024];
  __shared__ int carry_s;
  if (threadIdx.x == 0) carry_s = 0;
  __syncthreads();
  for (int base = 0; base < NN; base += 1024) {
    int i = base + (int)threadIdx.x;
    int v = (i < NN) ? deg[i] : 0;
    int c0 = carry_s;
    tmp[threadIdx.x] = v;
    __syncthreads();
    for (int s = 1; s < 1024; s <<= 1) {
      int add = (threadIdx.x >= (unsigned)s) ? tmp[threadIdx.x - s] : 0;
      __syncthreads();
      tmp[threadIdx.x] += add;
      __syncthreads();
    }
    if (i < NN) offs[i] = c0 + tmp[threadIdx.x] - v;   // exclusive
    int tot = tmp[1023];
    __syncthreads();
    if (threadIdx.x == 0) carry_s = c0 + tot;
    __syncthreads();
  }
  if (threadIdx.x == 0) offs[NN] = carry_s;
}

__global__ __launch_bounds__(256) void k_scatter(const int* __restrict__ src, const int* __restrict__ dst,
                                                 const float* __restrict__ w, const int* __restrict__ offs,
                                                 int* __restrict__ cursor, int* __restrict__ csr_src,
                                                 float* __restrict__ csr_w) {
  int e = blockIdx.x * 256 + threadIdx.x;
  if (e < NE) {
    int d = dst[e];
    int slot = offs[d] + atomicAdd(&cursor[d], 1);
    csr_src[slot] = src[e];
    csr_w[slot] = w[e];
  }
}

// ---------------- weight fusion ----------------
// fw[h*64+o, d] = sum_f ofc_w[o,f] * fc_w[h*64+f, d]
__global__ __launch_bounds__(256) void k_fuse_w(const float* __restrict__ fc_w, const float* __restrict__ ofc_w,
                                                float* __restrict__ fw) {
  int r = blockIdx.x;        // 0..255 = h*64+o
  int d = threadIdx.x;       // 0..255
  int h = r >> 6, o = r & 63;
  float acc = 0.f;
  for (int f = 0; f < 64; ++f)
    acc = fmaf(ofc_w[(o << 6) + f], fc_w[(((h << 6) + f) << 8) + d], acc);
  fw[(r << 8) + d] = acc;
}

// alf rows 0..3 = al_fused[h, d], rows 4..7 = ar_fused[h, d]
__global__ __launch_bounds__(256) void k_fuse_attn(const float* __restrict__ fc_w,
                                                   const float* __restrict__ al, const float* __restrict__ ar,
                                                   float* __restrict__ alf) {
  int r = blockIdx.x;        // 0..7
  int d = threadIdx.x;
  int h = r & 3;
  const float* a = (r < 4) ? al : ar;
  float acc = 0.f;
  for (int f = 0; f < 64; ++f)
    acc = fmaf(a[(h << 6) + f], fc_w[(((h << 6) + f) << 8) + d], acc);
  alf[(r << 8) + d] = acc;
}

// ---------------- GEMM: out[orow, c] = sum_k A[ra, k] * W[c, k] (+bias) ----------------
__global__ __launch_bounds__(256) void k_gemm(
    const float* __restrict__ pA0, const float* __restrict__ pA1,
    int lda, int half, int K,
    const float* __restrict__ W, int ldw,
    const float* __restrict__ bias,
    float* __restrict__ outp, int ldo, int permute)
{
  __shared__ float As[16][68];
  __shared__ float Bs[16][136];
  const int tid = threadIdx.x;
  const int lk = tid & 15;
  const int lm = tid >> 4;
  const int ra0 = blockIdx.x * 64;
  const int c0 = blockIdx.y * 128;
  float acc[4][8];
#pragma unroll
  for (int i = 0; i < 4; ++i)
#pragma unroll
    for (int j = 0; j < 8; ++j) acc[i][j] = 0.f;

  for (int k0 = 0; k0 < K; k0 += 16) {
    int k = k0 + lk;
    const float* pa = (k < half) ? (pA0 + (size_t)lda * (ra0 + lm) + k)
                                 : (pA1 + (size_t)lda * (ra0 + lm) + (k - half));
#pragma unroll
    for (int j = 0; j < 4; ++j)
      As[lk][lm + 16 * j] = pa[(size_t)lda * 16 * j];
    const float* pb = W + (size_t)ldw * (c0 + lm) + k;
#pragma unroll
    for (int j = 0; j < 8; ++j)
      Bs[lk][lm + 16 * j] = pb[(size_t)ldw * 16 * j];
    __syncthreads();
    const int tm = (tid >> 4) << 2;   // 0..60
    const int tn = (tid & 15) << 3;   // 0..120
#pragma unroll
    for (int kk = 0; kk < 16; ++kk) {
      float4 av  = *(const float4*)&As[kk][tm];
      float4 bv0 = *(const float4*)&Bs[kk][tn];
      float4 bv1 = *(const float4*)&Bs[kk][tn + 4];
      float a_[4] = {av.x, av.y, av.z, av.w};
      float b_[8] = {bv0.x, bv0.y, bv0.z, bv0.w, bv1.x, bv1.y, bv1.z, bv1.w};
#pragma unroll
      for (int i = 0; i < 4; ++i)
#pragma unroll
        for (int j = 0; j < 8; ++j)
          acc[i][j] = fmaf(a_[i], b_[j], acc[i][j]);
    }
    __syncthreads();
  }
  const int tm = (tid >> 4) << 2;
  const int tn = (tid & 15) << 3;
#pragma unroll
  for (int i = 0; i < 4; ++i) {
    int ra = ra0 + tm + i;
    int orow = permute ? ((ra % NN) * NB + ra / NN) : ra;
    float* po = outp + (size_t)orow * ldo + c0 + tn;
#pragma unroll
    for (int j = 0; j < 8; ++j) {
      float v = acc[i][j];
      if (bias) v += bias[c0 + tn + j];
      po[j] = v;
    }
  }
}

// ---------------- el/er: el[n*16+b*4+h] = sum_d x[ra,d]*alf[h,d] ----------------
__global__ __launch_bounds__(256) void k_eler2(
    const float* __restrict__ pA0, const float* __restrict__ pA1, int lda, int half,
    const float* __restrict__ alf, float* __restrict__ el, float* __restrict__ er)
{
  int wid = threadIdx.x >> 6, lane = threadIdx.x & 63;
  int ra = blockIdx.x * 4 + wid;        // 0..39999 = b*NN+n
  int k0 = lane << 2;
  const float* p = (k0 < half) ? (pA0 + (size_t)ra * lda + k0)
                               : (pA1 + (size_t)ra * lda + (k0 - half));
  float4 xv = *(const float4*)p;
  int n = ra % NN, b = ra / NN;
  int tb = (n << 4) + (b << 2);
#pragma unroll
  for (int oi = 0; oi < 8; ++oi) {
    float4 av = *(const float4*)(alf + (oi << 8) + k0);
    float s = xv.x * av.x + xv.y * av.y + xv.z * av.z + xv.w * av.w;
#pragma unroll
    for (int k = 32; k; k >>= 1) s += __shfl_xor(s, k);
    if (lane == 0) {
      if (oi < 4) el[tb + oi] = s;
      else        er[tb + (oi - 4)] = s;
    }
  }
}

// ---------------- edge softmax + aggregate, block-per-node ----------------
// block = 256 threads, one block per node n; covers all 16 (b,h) at once.
// score phase:   thread = (g = t>>4 edge-slot, bh_s = t&15)
// aggregate:     thread = (bh_a = t>>4, o4 = (t&15)*4 channels), float4 loads
__global__ __launch_bounds__(256) void k_edge2(
    const float* __restrict__ featW, const float* __restrict__ el, const float* __restrict__ er,
    const int* __restrict__ csr_src, const float* __restrict__ csr_w, const int* __restrict__ offs,
    const float* __restrict__ b2, float* __restrict__ outl)
{
  __shared__ int   esrc[MAXC];
  __shared__ float ew[MAXC];
  __shared__ float sc[MAXC][17];   // scores -> unnormalized alpha (in place)
  __shared__ float pm[16][16];     // partial max / partial sum
  __shared__ float er_s[16];
  __shared__ float mrun[16], srun[16], sl[16];
  const int t = threadIdx.x;
  const int n = blockIdx.x;
  const int s0 = offs[n], s1 = offs[n + 1];
  const int bh_s = t & 15;
  const int g    = t >> 4;
  const int bh_a = t >> 4;
  const int o4   = (t & 15) << 2;
  if (t < 16) { er_s[t] = er[(n << 4) + t]; mrun[t] = -INFINITY; srun[t] = 0.f; }
  float acc0 = 0.f, acc1 = 0.f, acc2 = 0.f, acc3 = 0.f;

  for (int c0 = s0; c0 < s1; c0 += MAXC) {
    const int csz = min(MAXC, s1 - c0);
    if (t < csz) { esrc[t] = csr_src[c0 + t]; ew[t] = csr_w[c0 + t]; }
    __syncthreads();
    // ---- scores (each computed exactly once) ----
    for (int eb = 0; eb < csz; eb += 16) {
      int e = eb + g;
      if (e < csz) {
        int src = esrc[e];
        float x = el[(src << 4) + bh_s] + er_s[bh_s];
        x = (x > 0.f) ? x : 0.1f * x;
        sc[e][bh_s] = x * ew[e];
      }
    }
    __syncthreads();
    // ---- chunk max per bh ----
    float pmax = -INFINITY;
    for (int e = g; e < csz; e += 16) pmax = fmaxf(pmax, sc[e][bh_s]);
    pm[g][bh_s] = pmax;
    __syncthreads();
    for (int st = 8; st; st >>= 1) {
      if (g < st) pm[g][bh_s] = fmaxf(pm[g][bh_s], pm[g + st][bh_s]);
      __syncthreads();
    }
    if (t < 16) {
      float mo = mrun[t];
      float mn = fmaxf(mo, pm[0][t]);
      mrun[t] = mn;
      sl[t] = (mo == -INFINITY) ? 0.f : __expf(mo - mn);
    }
    __syncthreads();
    // ---- exp + chunk sum per bh ----
    float m_bh = mrun[bh_s];
    float psum = 0.f;
    for (int e = g; e < csz; e += 16) {
      float ex = __expf(sc[e][bh_s] - m_bh);
      sc[e][bh_s] = ex;
      psum += ex;
    }
    pm[g][bh_s] = psum;
    __syncthreads();
    for (int st = 8; st; st >>= 1) {
      if (g < st) pm[g][bh_s] += pm[g + st][bh_s];
      __syncthreads();
    }
    if (t < 16) srun[t] = srun[t] * sl[t] + pm[0][t];
    __syncthreads();
    // ---- rescale + aggregate (float4, fully coalesced 4KB/edge per block) ----
    float scl = sl[bh_a];
    acc0 *= scl; acc1 *= scl; acc2 *= scl; acc3 *= scl;
    for (int e = 0; e < csz; ++e) {
      float a = sc[e][bh_a];                       // LDS broadcast
      int src = esrc[e];
      const float4 f = *(const float4*)(featW + ((((size_t)src << 4) + bh_a) << 6) + o4);
      acc0 = fmaf(a, f.x, acc0);
      acc1 = fmaf(a, f.y, acc1);
      acc2 = fmaf(a, f.z, acc2);
      acc3 = fmaf(a, f.w, acc3);
    }
    __syncthreads();   // protect LDS before next chunk
  }

  float invs = (s1 > s0) ? 1.f / srun[bh_a] : 0.f;
  const float4 bv = *(const float4*)(b2 + o4);
  float4 r;
  r.x = fmaxf(fmaf(acc0, invs, bv.x), 0.f);
  r.y = fmaxf(fmaf(acc1, invs, bv.y), 0.f);
  r.z = fmaxf(fmaf(acc2, invs, bv.z), 0.f);
  r.w = fmaxf(fmaf(acc3, invs, bv.w), 0.f);
  const int b = bh_a >> 2, h = bh_a & 3;
  *(float4*)(outl + (((size_t)b * NN + n) << 8) + (h << 6) + o4) = r;
}

// ---------------- launch ----------------
extern "C" void kernel_launch(void* const* d_in, const int* in_sizes, int n_in,
                              void* d_out, int out_size, void* d_ws, size_t ws_size,
                              hipStream_t stream) {
  const float* sol    = (const float*)d_in[0];   // [2,4,10000,128]
  const float* w      = (const float*)d_in[1];   // [E]
  const float* fc_w   = (const float*)d_in[2];   // [2,256,256]
  const float* attn_l = (const float*)d_in[3];   // [2,4,64]
  const float* attn_r = (const float*)d_in[4];   // [2,4,64]
  const float* ofc_w  = (const float*)d_in[5];   // [2,64,64]
  const float* ofc_b  = (const float*)d_in[6];   // [2,64]
  const float* mlp_w  = (const float*)d_in[7];   // [256,512]
  const float* mlp_b  = (const float*)d_in[8];   // [256]
  const int*   d_src  = (const int*)d_in[9];     // [E]
  const int*   d_dst  = (const int*)d_in[10];    // [E]
  float* out = (float*)d_out;

  char* p = (char*)d_ws;
  auto alloc = [&](size_t bytes) { char* r = p; p += (bytes + 255) & ~(size_t)255; return r; };
  float* featW   = (float*)alloc((size_t)NT * NDH * 4);     // 40.96 MB
  float* out0    = (float*)alloc((size_t)NM * ND * 4);      // 40.96 MB
  float* out1    = (float*)alloc((size_t)NM * ND * 4);      // 40.96 MB
  float* el      = (float*)alloc((size_t)NT * 4);
  float* er      = (float*)alloc((size_t)NT * 4);
  int*   deg     = (int*)alloc((size_t)(NN + 1) * 4);
  int*   offs    = (int*)alloc((size_t)(NN + 1) * 4);
  int*   cursor  = (int*)alloc((size_t)NN * 4);
  int*   csr_src = (int*)alloc((size_t)NE * 4);
  float* csr_w   = (float*)alloc((size_t)NE * 4);
  float* fw      = (float*)alloc((size_t)ND * ND * 4);
  float* alf     = (float*)alloc((size_t)8 * ND * 4);
  if ((size_t)(p - (char*)d_ws) > ws_size) return;  // fail loudly (validation will catch)

  hipMemsetAsync(deg, 0, (size_t)NN * 4, stream);
  hipMemsetAsync(cursor, 0, (size_t)NN * 4, stream);
  k_deg<<<NE / 256, 256, 0, stream>>>(d_dst, deg);
  k_scan<<<1, 1024, 0, stream>>>(deg, offs);
  k_scatter<<<NE / 256, 256, 0, stream>>>(d_src, d_dst, w, offs, cursor, csr_src, csr_w);

  for (int l = 0; l < 2; ++l) {
    const float* fcl = fc_w + (size_t)l * ND * ND;
    k_fuse_w<<<256, 256, 0, stream>>>(fcl, ofc_w + (size_t)l * NDH * NDH, fw);
    k_fuse_attn<<<8, 256, 0, stream>>>(fcl, attn_l + (size_t)l * NH * NDH, attn_r + (size_t)l * NH * NDH, alf);
    const float* pA0; const float* pA1; int lda, half;
    if (l == 0) { pA0 = sol; pA1 = sol + (size_t)NB * NN * 128; lda = 128; half = 128; }
    else        { pA0 = out0; pA1 = out0; lda = 256; half = 256; }
    k_gemm<<<dim3(NM / 64, ND / 128), 256, 0, stream>>>(pA0, pA1, lda, half, ND,
                                                        fw, ND, nullptr, featW, ND, 1);
    k_eler2<<<NM / 4, 256, 0, stream>>>(pA0, pA1, lda, half, alf, el, er);
    k_edge2<<<NN, 256, 0, stream>>>(featW, el, er, csr_src, csr_w, offs,
                                    ofc_b + (size_t)l * NDH, (l == 0) ? out0 : out1);
  }

  // final MLP: out[b,n,o] = concat(out0,out1)[row,:512] . mlp_w[o,:] + mlp_b[o]
  k_gemm<<<dim3(NM / 64, ND / 128), 256, 0, stream>>>(out0, out1, 256, 256, 512,
                                                      mlp_w, 512, mlp_b, out, ND, 0);
}

// Round 3
// 297.810 us; speedup vs baseline: 3.1677x; 2.1289x over previous
//
#include <hip/hip_runtime.h>
#include <math.h>

#define NN 10000
#define NE 160000
#define NB 4
#define NH 4
#define ND 256
#define NT (NN * 16)        // (n,b,h) triples
#define NM 40000            // GEMM rows (b*NN+n)
#define MAXC 64

typedef _Float16 f16;
typedef _Float16 half8 __attribute__((ext_vector_type(8)));
typedef float f32x4 __attribute__((ext_vector_type(4)));

union H4 { uint2 u; f16 h[4]; };

__device__ __forceinline__ void gload_lds16(const void* g, void* l) {
  __builtin_amdgcn_global_load_lds((const __attribute__((address_space(1))) void*)g,
                                   (__attribute__((address_space(3))) void*)l, 16, 0, 0);
}

// ---------------- CSR build ----------------
__global__ __launch_bounds__(256) void k_deg(const int* __restrict__ dst, int* __restrict__ deg) {
  int e = blockIdx.x * 256 + threadIdx.x;
  if (e < NE) atomicAdd(&deg[dst[e]], 1);
}

__global__ __launch_bounds__(1024) void k_scan(const int* __restrict__ deg, int* __restrict__ offs) {
  __shared__ int tmp[1024];
  __shared__ int carry_s;
  if (threadIdx.x == 0) carry_s = 0;
  __syncthreads();
  for (int base = 0; base < NN; base += 1024) {
    int i = base + (int)threadIdx.x;
    int v = (i < NN) ? deg[i] : 0;
    int c0 = carry_s;
    tmp[threadIdx.x] = v;
    __syncthreads();
    for (int s = 1; s < 1024; s <<= 1) {
      int add = (threadIdx.x >= (unsigned)s) ? tmp[threadIdx.x - s] : 0;
      __syncthreads();
      tmp[threadIdx.x] += add;
      __syncthreads();
    }
    if (i < NN) offs[i] = c0 + tmp[threadIdx.x] - v;   // exclusive
    int tot = tmp[1023];
    __syncthreads();
    if (threadIdx.x == 0) carry_s = c0 + tot;
    __syncthreads();
  }
  if (threadIdx.x == 0) offs[NN] = carry_s;
}

__global__ __launch_bounds__(256) void k_scatter(const int* __restrict__ src, const int* __restrict__ dst,
                                                 const float* __restrict__ w, const int* __restrict__ offs,
                                                 int* __restrict__ cursor, int* __restrict__ csr_src,
                                                 float* __restrict__ csr_w) {
  int e = blockIdx.x * 256 + threadIdx.x;
  if (e < NE) {
    int d = dst[e];
    int slot = offs[d] + atomicAdd(&cursor[d], 1);
    csr_src[slot] = src[e];
    csr_w[slot] = w[e];
  }
}

// ---------------- converters ----------------
// solutions [2][B*NN][128] fp32 -> solh [B*NN][256] fp16 (concat along feature dim)
__global__ __launch_bounds__(256) void k_cvt_sol(const float* __restrict__ sol, f16* __restrict__ solh) {
  int i = blockIdx.x * 256 + threadIdx.x;   // 2.56M quads
  int row = i >> 6, q = i & 63;
  int k = q << 2;
  const float* s = (k < 128) ? (sol + (size_t)row * 128 + k)
                             : (sol + (size_t)(NM + row) * 128 + (k - 128));
  float4 v = *(const float4*)s;
  H4 h;
  h.h[0] = (f16)v.x; h.h[1] = (f16)v.y; h.h[2] = (f16)v.z; h.h[3] = (f16)v.w;
  *(uint2*)(solh + (size_t)row * 256 + k) = h.u;
}

__global__ __launch_bounds__(256) void k_cvt4(const float* __restrict__ in, f16* __restrict__ out, int n4) {
  int i = blockIdx.x * 256 + threadIdx.x;
  if (i < n4) {
    float4 v = *(const float4*)(in + (size_t)i * 4);
    H4 h;
    h.h[0] = (f16)v.x; h.h[1] = (f16)v.y; h.h[2] = (f16)v.z; h.h[3] = (f16)v.w;
    *(uint2*)(out + (size_t)i * 4) = h.u;
  }
}

// ---------------- weight fusion ----------------
// fwh[h*64+o, d] = sum_f ofc_w[o,f] * fc_w[h*64+f, d]   (fp16 out)
__global__ __launch_bounds__(256) void k_fuse_wh(const float* __restrict__ fc_w, const float* __restrict__ ofc_w,
                                                 f16* __restrict__ fwh) {
  int r = blockIdx.x;        // 0..255 = h*64+o
  int d = threadIdx.x;       // 0..255
  int h = r >> 6, o = r & 63;
  float acc = 0.f;
  for (int f = 0; f < 64; ++f)
    acc = fmaf(ofc_w[(o << 6) + f], fc_w[(((h << 6) + f) << 8) + d], acc);
  fwh[(r << 8) + d] = (f16)acc;
}

// alf rows 0..3 = al_fused[h, d], rows 4..7 = ar_fused[h, d]  (fp32)
__global__ __launch_bounds__(256) void k_fuse_attn(const float* __restrict__ fc_w,
                                                   const float* __restrict__ al, const float* __restrict__ ar,
                                                   float* __restrict__ alf) {
  int r = blockIdx.x;        // 0..7
  int d = threadIdx.x;
  int h = r & 3;
  const float* a = (r < 4) ? al : ar;
  float acc = 0.f;
  for (int f = 0; f < 64; ++f)
    acc = fmaf(a[(h << 6) + f], fc_w[(((h << 6) + f) << 8) + d], acc);
  alf[(r << 8) + d] = acc;
}

// ---------------- MFMA fp16 GEMM ----------------
// out[orow, c] = sum_k A[ra, k] * W[c, k] (+bias)
// A fp16 [M rows, lda], W fp16 [cols][K] (row-major K), block tile 64x128, 4 waves (32x64 each)
template<int PERM, int OUTH>
__global__ __launch_bounds__(256) void k_gemm_f16(
    const f16* __restrict__ A, int lda, int K,
    const f16* __restrict__ W,
    const float* __restrict__ bias,
    void* __restrict__ outp, int ldo)
{
  __shared__ __align__(16) f16 As[64 * 32];    // [row][k] 4KB
  __shared__ __align__(16) f16 Bs[128 * 32];   // [col][k] 8KB
  const int tid = threadIdx.x;
  const int lane = tid & 63;
  const int w = tid >> 6;
  const int wr = w >> 1, wc = w & 1;
  const int ra0 = blockIdx.x * 64;
  const int c0 = blockIdx.y * 128;
  const int l2 = lane >> 2;            // 0..15: row within 16-row panel
  const int lk8 = (lane & 3) * 8;      // 0,8,16,24: k offset (halfs)

  f32x4 acc[2][4];
#pragma unroll
  for (int mr = 0; mr < 2; ++mr)
#pragma unroll
    for (int nr = 0; nr < 4; ++nr) acc[mr][nr] = (f32x4)0.f;

  const int fr = lane & 15;
  const int fg = (lane >> 4) * 8;

  for (int k0 = 0; k0 < K; k0 += 32) {
    // stage A: wave w -> rows 16w..16w+15 (1KB, lane-linear)
    gload_lds16(A + (size_t)(ra0 + 16 * w + l2) * lda + k0 + lk8, As + w * 512);
    // stage B: wave w -> cols 32w..32w+31 (2 x 1KB)
    gload_lds16(W + (size_t)(c0 + 32 * w + l2) * K + k0 + lk8, Bs + w * 1024);
    gload_lds16(W + (size_t)(c0 + 32 * w + 16 + l2) * K + k0 + lk8, Bs + w * 1024 + 512);
    __syncthreads();

    half8 af[2], bf[4];
#pragma unroll
    for (int mr = 0; mr < 2; ++mr)
      af[mr] = *(const half8*)(As + (wr * 32 + mr * 16 + fr) * 32 + fg);
#pragma unroll
    for (int nr = 0; nr < 4; ++nr)
      bf[nr] = *(const half8*)(Bs + (wc * 64 + nr * 16 + fr) * 32 + fg);
#pragma unroll
    for (int mr = 0; mr < 2; ++mr)
#pragma unroll
      for (int nr = 0; nr < 4; ++nr)
        acc[mr][nr] = __builtin_amdgcn_mfma_f32_16x16x32_f16(af[mr], bf[nr], acc[mr][nr], 0, 0, 0);
    __syncthreads();
  }

  const int r0 = (lane >> 4) * 4;
#pragma unroll
  for (int nr = 0; nr < 4; ++nr) {
    int col = c0 + wc * 64 + nr * 16 + fr;
    float bv = bias ? bias[col] : 0.f;
#pragma unroll
    for (int mr = 0; mr < 2; ++mr) {
      f32x4 v = acc[mr][nr];
#pragma unroll
      for (int r = 0; r < 4; ++r) {
        int ra = ra0 + wr * 32 + mr * 16 + r0 + r;
        int orow = PERM ? ((ra % NN) * NB + ra / NN) : ra;
        float val = v[r] + bv;
        if (OUTH) ((f16*)outp)[(size_t)orow * ldo + col] = (f16)val;
        else      ((float*)outp)[(size_t)orow * ldo + col] = val;
      }
    }
  }
}

// ---------------- el/er from fp16 x ----------------
__global__ __launch_bounds__(256) void k_eler2h(
    const f16* __restrict__ xh, int lda,
    const float* __restrict__ alf, float* __restrict__ el, float* __restrict__ er)
{
  int wid = threadIdx.x >> 6, lane = threadIdx.x & 63;
  int ra = blockIdx.x * 4 + wid;        // b*NN+n
  int k0 = lane << 2;
  H4 hv;
  hv.u = *(const uint2*)(xh + (size_t)ra * lda + k0);
  float x0 = (float)hv.h[0], x1 = (float)hv.h[1], x2 = (float)hv.h[2], x3 = (float)hv.h[3];
  int n = ra % NN, b = ra / NN;
  int tb = (n << 4) + (b << 2);
#pragma unroll
  for (int oi = 0; oi < 8; ++oi) {
    float4 av = *(const float4*)(alf + (oi << 8) + k0);
    float s = x0 * av.x + x1 * av.y + x2 * av.z + x3 * av.w;
#pragma unroll
    for (int k = 32; k; k >>= 1) s += __shfl_xor(s, k);
    if (lane == 0) {
      if (oi < 4) el[tb + oi] = s;
      else        er[tb + (oi - 4)] = s;
    }
  }
}

// ---------------- edge softmax + aggregate, block-per-node (fp16 feats) ----------------
__global__ __launch_bounds__(256) void k_edge2h(
    const f16* __restrict__ featWh, const float* __restrict__ el, const float* __restrict__ er,
    const int* __restrict__ csr_src, const float* __restrict__ csr_w, const int* __restrict__ offs,
    const float* __restrict__ b2, f16* __restrict__ outh)
{
  __shared__ int   esrc[MAXC];
  __shared__ float ew[MAXC];
  __shared__ float sc[MAXC][17];
  __shared__ float pm[16][16];
  __shared__ float er_s[16];
  __shared__ float mrun[16], srun[16], sl[16];
  const int t = threadIdx.x;
  const int n = blockIdx.x;
  const int s0 = offs[n], s1 = offs[n + 1];
  const int bh_s = t & 15;
  const int g    = t >> 4;
  const int bh_a = t >> 4;
  const int o4   = (t & 15) << 2;
  if (t < 16) { er_s[t] = er[(n << 4) + t]; mrun[t] = -INFINITY; srun[t] = 0.f; }
  float acc0 = 0.f, acc1 = 0.f, acc2 = 0.f, acc3 = 0.f;

  for (int c0 = s0; c0 < s1; c0 += MAXC) {
    const int csz = min(MAXC, s1 - c0);
    if (t < csz) { esrc[t] = csr_src[c0 + t]; ew[t] = csr_w[c0 + t]; }
    __syncthreads();
    for (int eb = 0; eb < csz; eb += 16) {
      int e = eb + g;
      if (e < csz) {
        int src = esrc[e];
        float x = el[(src << 4) + bh_s] + er_s[bh_s];
        x = (x > 0.f) ? x : 0.1f * x;
        sc[e][bh_s] = x * ew[e];
      }
    }
    __syncthreads();
    float pmax = -INFINITY;
    for (int e = g; e < csz; e += 16) pmax = fmaxf(pmax, sc[e][bh_s]);
    pm[g][bh_s] = pmax;
    __syncthreads();
    for (int st = 8; st; st >>= 1) {
      if (g < st) pm[g][bh_s] = fmaxf(pm[g][bh_s], pm[g + st][bh_s]);
      __syncthreads();
    }
    if (t < 16) {
      float mo = mrun[t];
      float mn = fmaxf(mo, pm[0][t]);
      mrun[t] = mn;
      sl[t] = (mo == -INFINITY) ? 0.f : __expf(mo - mn);
    }
    __syncthreads();
    float m_bh = mrun[bh_s];
    float psum = 0.f;
    for (int e = g; e < csz; e += 16) {
      float ex = __expf(sc[e][bh_s] - m_bh);
      sc[e][bh_s] = ex;
      psum += ex;
    }
    pm[g][bh_s] = psum;
    __syncthreads();
    for (int st = 8; st; st >>= 1) {
      if (g < st) pm[g][bh_s] += pm[g + st][bh_s];
      __syncthreads();
    }
    if (t < 16) srun[t] = srun[t] * sl[t] + pm[0][t];
    __syncthreads();
    float scl = sl[bh_a];
    acc0 *= scl; acc1 *= scl; acc2 *= scl; acc3 *= scl;
    for (int e = 0; e < csz; ++e) {
      float a = sc[e][bh_a];
      int src = esrc[e];
      H4 fv;
      fv.u = *(const uint2*)(featWh + ((((size_t)src << 4) + bh_a) << 6) + o4);
      acc0 = fmaf(a, (float)fv.h[0], acc0);
      acc1 = fmaf(a, (float)fv.h[1], acc1);
      acc2 = fmaf(a, (float)fv.h[2], acc2);
      acc3 = fmaf(a, (float)fv.h[3], acc3);
    }
    __syncthreads();
  }

  float invs = (s1 > s0) ? 1.f / srun[bh_a] : 0.f;
  const float4 bv = *(const float4*)(b2 + o4);
  const int b = bh_a >> 2, h = bh_a & 3;
  H4 o;
  o.h[0] = (f16)fmaxf(fmaf(acc0, invs, bv.x), 0.f);
  o.h[1] = (f16)fmaxf(fmaf(acc1, invs, bv.y), 0.f);
  o.h[2] = (f16)fmaxf(fmaf(acc2, invs, bv.z), 0.f);
  o.h[3] = (f16)fmaxf(fmaf(acc3, invs, bv.w), 0.f);
  *(uint2*)(outh + ((size_t)b * NN + n) * 512 + (h << 6) + o4) = o.u;
}

// ---------------- launch ----------------
extern "C" void kernel_launch(void* const* d_in, const int* in_sizes, int n_in,
                              void* d_out, int out_size, void* d_ws, size_t ws_size,
                              hipStream_t stream) {
  const float* sol    = (const float*)d_in[0];   // [2,4,10000,128]
  const float* w      = (const float*)d_in[1];   // [E]
  const float* fc_w   = (const float*)d_in[2];   // [2,256,256]
  const float* attn_l = (const float*)d_in[3];   // [2,4,64]
  const float* attn_r = (const float*)d_in[4];   // [2,4,64]
  const float* ofc_w  = (const float*)d_in[5];   // [2,64,64]
  const float* ofc_b  = (const float*)d_in[6];   // [2,64]
  const float* mlp_w  = (const float*)d_in[7];   // [256,512]
  const float* mlp_b  = (const float*)d_in[8];   // [256]
  const int*   d_src  = (const int*)d_in[9];     // [E]
  const int*   d_dst  = (const int*)d_in[10];    // [E]
  float* out = (float*)d_out;

  char* p = (char*)d_ws;
  auto alloc = [&](size_t bytes) { char* r = p; p += (bytes + 255) & ~(size_t)255; return r; };
  f16*   solh    = (f16*)alloc((size_t)NM * 256 * 2);      // 20.5 MB
  f16*   out01h  = (f16*)alloc((size_t)NM * 512 * 2);      // 41 MB (layer0 cols 0-255, layer1 cols 256-511)
  f16*   featWh  = (f16*)alloc((size_t)NT * 64 * 2);       // 20.5 MB
  f16*   fwh     = (f16*)alloc((size_t)ND * ND * 2);
  f16*   mlph    = (f16*)alloc((size_t)ND * 512 * 2);
  float* el      = (float*)alloc((size_t)NT * 4);
  float* er      = (float*)alloc((size_t)NT * 4);
  float* alf     = (float*)alloc((size_t)8 * ND * 4);
  int*   deg     = (int*)alloc((size_t)(NN + 1) * 4);
  int*   offs    = (int*)alloc((size_t)(NN + 1) * 4);
  int*   cursor  = (int*)alloc((size_t)NN * 4);
  int*   csr_src = (int*)alloc((size_t)NE * 4);
  float* csr_w   = (float*)alloc((size_t)NE * 4);
  if ((size_t)(p - (char*)d_ws) > ws_size) return;

  hipMemsetAsync(deg, 0, (size_t)NN * 4, stream);
  hipMemsetAsync(cursor, 0, (size_t)NN * 4, stream);
  k_deg<<<NE / 256, 256, 0, stream>>>(d_dst, deg);
  k_scan<<<1, 1024, 0, stream>>>(deg, offs);
  k_scatter<<<NE / 256, 256, 0, stream>>>(d_src, d_dst, w, offs, cursor, csr_src, csr_w);

  k_cvt_sol<<<NM * 64 / 256, 256, 0, stream>>>(sol, solh);
  k_cvt4<<<(ND * 512 / 4 + 255) / 256, 256, 0, stream>>>(mlp_w, mlph, ND * 512 / 4);

  for (int l = 0; l < 2; ++l) {
    const float* fcl = fc_w + (size_t)l * ND * ND;
    k_fuse_wh<<<256, 256, 0, stream>>>(fcl, ofc_w + (size_t)l * 64 * 64, fwh);
    k_fuse_attn<<<8, 256, 0, stream>>>(fcl, attn_l + (size_t)l * NH * 64, attn_r + (size_t)l * NH * 64, alf);
    const f16* Ah = (l == 0) ? solh : out01h;
    int lda = (l == 0) ? 256 : 512;
    k_gemm_f16<1, 1><<<dim3(NM / 64, ND / 128), 256, 0, stream>>>(
        Ah, lda, 256, fwh, nullptr, featWh, 256);
    k_eler2h<<<NM / 4, 256, 0, stream>>>(Ah, lda, alf, el, er);
    k_edge2h<<<NN, 256, 0, stream>>>(featWh, el, er, csr_src, csr_w, offs,
                                     ofc_b + (size_t)l * 64, out01h + (l == 0 ? 0 : 256));
  }

  // final MLP: out[b,n,o] = concat(out0,out1)[row,:512] . mlp_w[o,:] + mlp_b[o]
  k_gemm_f16<0, 0><<<dim3(NM / 64, ND / 128), 256, 0, stream>>>(
      out01h, 512, 512, mlph, mlp_b, out, 256);
}